// Round 7
// baseline (704.800 us; speedup 1.0000x reference)
//
#include <hip/hip_runtime.h>
#include <hip/hip_cooperative_groups.h>
#include <math.h>

namespace cg = cooperative_groups;

#define RAD 5
#define SIDE 80
#define SLAB 6400      // 80*80
#define VOL 512000     // 80^3
#define NCH 8          // N*K
#define NCLS 4
#define TW 16          // tile extent along the convolved axis
#define NT 5           // tiles per axis (80/16)
#define CPART (SIDE*NT)        // 400 partials per channel
#define NBLK (NCH*SIDE*NT)     // 3200 tiles
#define Q 20           // float4 columns per 80-float row
#define TAS 24         // tA row stride in float4 (96 floats: 2-f4 pad both sides)
#define TBS 21         // tB/tile row stride in float4
#define GRID 1536      // cooperative grid: 6 blocks/CU co-resident

// exp(-t^2/32) for t=-5..5 (unnormalized Gaussian, symmetric)
__constant__ float GW[11] = {
    0.45783336177161427f, 0.6065306597126334f, 0.7548396019890073f,
    0.8824969025845955f,  0.969233234476344f,  1.0f,
    0.969233234476344f,   0.8824969025845955f, 0.7548396019890073f,
    0.6065306597126334f,  0.45783336177161427f};

// Module-scope scratch (no d_ws dependence). All written-before-read each call.
__device__ float  g_bufT[(size_t)NCH * VOL];  // d+w-conv'd labels, [c][w][h][d]
__device__ float2 g_part1[NBLK];              // {S_ip, S_p} per tile
__device__ float2 g_part2[NBLK];              // {num, den} per tile

// ---------------- per-tile bodies (shared by fused + fallback) ----------------

// Phase A tile: channel sums + conv D + conv W, transposed store to g_bufT.
__device__ __forceinline__ void tileA_body(int tile,
        const float* __restrict__ labels, const float* __restrict__ img,
        float4* tA, float4* tB, float* sm) {
    const int c   = tile / (SIDE * NT);
    const int rem = tile % (SIDE * NT);
    const int h   = rem / NT;
    const int w0  = (rem % NT) * TW;
    const int n   = c >> 2;

    // zero the d-pad columns only (f4 idx 0,1,22,23 per row)
    for (int i = threadIdx.x; i < 26 * 4; i += 256) {
        int r = i >> 2, j = i & 3;
        tA[r * TAS + ((j < 2) ? j : (20 + j))] = make_float4(0.f, 0.f, 0.f, 0.f);
    }
    // load labels rows; OOB halo rows store zero
    const float* labc = labels + ((size_t)c * SIDE + h) * SLAB;   // [w][d] slab
    for (int i = threadIdx.x; i < 26 * Q; i += 256) {
        int r = i / Q, q = i - r * Q;
        int w = w0 - RAD + r;
        float4 v = (w >= 0 && w < SIDE)
                     ? ((const float4*)(labc + (size_t)w * SIDE))[q]
                     : make_float4(0.f, 0.f, 0.f, 0.f);
        tA[r * TAS + 2 + q] = v;
    }
    __syncthreads();

    // channel sums over the central 16 rows
    float sip = 0.f, sp = 0.f;
    const float4* imgc4 = (const float4*)(img + ((((size_t)n * SIDE + h) * SIDE + w0) * SIDE));
    for (int i = threadIdx.x; i < TW * Q; i += 256) {
        int rl = i / Q, q = i - rl * Q;
        float4 l = tA[(rl + RAD) * TAS + 2 + q];
        float4 v = imgc4[i];
        sip += l.x * v.x + l.y * v.y + l.z * v.z + l.w * v.w;
        sp  += l.x + l.y + l.z + l.w;
    }
    // conv along D: register window, 5 b128 reads -> 4 outputs
    for (int i = threadIdx.x; i < 26 * Q; i += 256) {
        int r = i / Q, q = i - r * Q;
        const float4* row = &tA[r * TAS + q];
        float a[20];
        #pragma unroll
        for (int j = 0; j < 5; ++j) {
            float4 v = row[j];
            a[4 * j] = v.x; a[4 * j + 1] = v.y; a[4 * j + 2] = v.z; a[4 * j + 3] = v.w;
        }
        float s0 = 0.f, s1 = 0.f, s2 = 0.f, s3 = 0.f;
        #pragma unroll
        for (int t = 0; t < 11; ++t) {
            float g = GW[t];
            s0 += g * a[t + 3]; s1 += g * a[t + 4];
            s2 += g * a[t + 5]; s3 += g * a[t + 6];
        }
        tB[r * TBS + q] = make_float4(s0, s1, s2, s3);
    }
    // block-reduce the sums
    #pragma unroll
    for (int off = 32; off > 0; off >>= 1) {
        sip += __shfl_down(sip, off);
        sp  += __shfl_down(sp, off);
    }
    const int lane = threadIdx.x & 63;
    const int wid  = threadIdx.x >> 6;
    if (lane == 0) { sm[wid * 2] = sip; sm[wid * 2 + 1] = sp; }
    __syncthreads();   // tB complete + sm visible
    if (threadIdx.x == 0)
        g_part1[tile] = make_float2(sm[0] + sm[2] + sm[4] + sm[6],
                                    sm[1] + sm[3] + sm[5] + sm[7]);
    // conv along W + transposed float4 store
    float* outc = g_bufT + (size_t)c * VOL + (size_t)h * SIDE;
    for (int i = threadIdx.x; i < TW * Q; i += 256) {
        int rl = i / Q, q = i - rl * Q;
        float sx = 0.f, sy = 0.f, sz = 0.f, sw = 0.f;
        #pragma unroll
        for (int t = 0; t < 11; ++t) {
            float g = GW[t];
            float4 v = tB[(rl + t) * TBS + q];
            sx += g * v.x; sy += g * v.y; sz += g * v.z; sw += g * v.w;
        }
        ((float4*)(outc + (size_t)(w0 + rl) * SLAB))[q] = make_float4(sx, sy, sz, sw);
    }
}

// Phase B tile: conv H of g_bufT + fused weight + dot with labels.
__device__ __forceinline__ void tileB_body(int tile,
        const float* __restrict__ labels, const float* __restrict__ img,
        float4* tile_s, float* sm, float* s_mean) {
    const int c   = tile / (SIDE * NT);
    const int rem = tile % (SIDE * NT);
    const int w   = rem / NT;
    const int h0  = (rem % NT) * TW;
    const int n   = c >> 2;

    // per-channel mean from phase-A partials (redundant per tile; L2-resident)
    float a = 0.f, b = 0.f;
    for (int t = threadIdx.x; t < CPART; t += 256) {
        float2 p = g_part1[c * CPART + t];
        a += p.x; b += p.y;
    }
    #pragma unroll
    for (int off = 32; off > 0; off >>= 1) {
        a += __shfl_down(a, off);
        b += __shfl_down(b, off);
    }
    const int lane = threadIdx.x & 63;
    const int wid  = threadIdx.x >> 6;
    if (lane == 0) { sm[wid * 2] = a; sm[wid * 2 + 1] = b; }

    // load tile (rows contiguous in g_bufT layout), zero OOB halo
    const float4* bc4 = (const float4*)(g_bufT + (size_t)c * VOL + (size_t)w * SLAB);
    for (int i = threadIdx.x; i < 26 * Q; i += 256) {
        int r = i / Q, q = i - r * Q;
        int hh = h0 - RAD + r;
        float4 v = (hh >= 0 && hh < SIDE) ? bc4[hh * Q + q]
                                          : make_float4(0.f, 0.f, 0.f, 0.f);
        tile_s[r * TBS + q] = v;
    }
    __syncthreads();
    if (threadIdx.x == 0)
        *s_mean = (sm[0] + sm[2] + sm[4] + sm[6]) /
                  (sm[1] + sm[3] + sm[5] + sm[7] + 5.12f);   // VOL*EPS_MEAN
    __syncthreads();
    const float mean = *s_mean;

    const float4* labp4 = (const float4*)(labels + (size_t)c * VOL);
    const float4* imgp4 = (const float4*)(img + (size_t)n * VOL);
    float num = 0.f, den = 0.f;
    for (int i = threadIdx.x; i < TW * Q; i += 256) {
        int hl = i / Q, q = i - hl * Q;
        float sx = 0.f, sy = 0.f, sz = 0.f, sw = 0.f;
        #pragma unroll
        for (int t = 0; t < 11; ++t) {
            float g = GW[t];
            float4 v = tile_s[(hl + t) * TBS + q];
            sx += g * v.x; sy += g * v.y; sz += g * v.z; sw += g * v.w;
        }
        size_t gi = ((size_t)(h0 + hl) * SIDE + w) * Q + q;   // float4 index
        float4 l = labp4[gi];
        float4 v = imgp4[gi];
        float d0 = v.x - mean, d1 = v.y - mean, d2 = v.z - mean, d3 = v.w - mean;
        float q0 = d0 * d0, q1 = d1 * d1, q2 = d2 * d2, q3 = d3 * d3;
        float w0_ = __expf(-q0 * q0), w1_ = __expf(-q1 * q1);
        float w2_ = __expf(-q2 * q2), w3_ = __expf(-q3 * q3);
        num += sx * l.x * w0_ + sy * l.y * w1_ + sz * l.z * w2_ + sw * l.w * w3_;
        den += sx * w0_ + sy * w1_ + sz * w2_ + sw * w3_;
    }
    #pragma unroll
    for (int off = 32; off > 0; off >>= 1) {
        num += __shfl_down(num, off);
        den += __shfl_down(den, off);
    }
    if (lane == 0) { sm[wid * 2] = num; sm[wid * 2 + 1] = den; }
    __syncthreads();
    if (threadIdx.x == 0)
        g_part2[tile] = make_float2(sm[0] + sm[2] + sm[4] + sm[6],
                                    sm[1] + sm[3] + sm[5] + sm[7]);
}

// Final reduce body: per-channel ratio -> loss scalar (single block).
__device__ __forceinline__ void final_body(float* __restrict__ out, float* sm) {
    __shared__ float cn[NCH], cd[NCH];
    const int lane = threadIdx.x & 63;
    const int wid  = threadIdx.x >> 6;
    for (int c = 0; c < NCH; ++c) {
        float a = 0.f, b = 0.f;
        for (int t = threadIdx.x; t < CPART; t += 256) {
            float2 p = g_part2[c * CPART + t];
            a += p.x; b += p.y;
        }
        #pragma unroll
        for (int off = 32; off > 0; off >>= 1) {
            a += __shfl_down(a, off);
            b += __shfl_down(b, off);
        }
        if (lane == 0) { sm[wid * 2] = a; sm[wid * 2 + 1] = b; }
        __syncthreads();
        if (threadIdx.x == 0) {
            cn[c] = sm[0] + sm[2] + sm[4] + sm[6];
            cd[c] = sm[1] + sm[3] + sm[5] + sm[7];
        }
        __syncthreads();
    }
    if (threadIdx.x == 0) {
        float loss = 0.f;
        for (int k = 0; k < NCLS; ++k) {
            float r0 = cn[k]        / (cd[k]        + 1e-6f);
            float r1 = cn[NCLS + k] / (cd[NCLS + k] + 1e-6f);
            loss += 0.5f * (fabsf(r0) + fabsf(r1));   // mean over N=2, sum over K
        }
        out[0] = (float)NCLS - loss;
    }
}

// ---------------- fused cooperative kernel ----------------
__global__ void __launch_bounds__(256, 6) fused_kernel(
        const float* __restrict__ labels, const float* __restrict__ img,
        float* __restrict__ out) {
    __shared__ float4 tA[26 * TAS];   // 9984 B (phase B reuses as tile buffer)
    __shared__ float4 tB[26 * TBS];   // 8736 B
    __shared__ float sm[8];
    __shared__ float s_mean;
    cg::grid_group grid = cg::this_grid();

    for (int tile = blockIdx.x; tile < NBLK; tile += GRID) {
        __syncthreads();               // protect tA/tB reuse across iterations
        tileA_body(tile, labels, img, tA, tB, sm);
    }
    __threadfence();
    grid.sync();

    for (int tile = blockIdx.x; tile < NBLK; tile += GRID) {
        __syncthreads();
        tileB_body(tile, labels, img, tA, sm, &s_mean);
    }
    __threadfence();
    grid.sync();

    if (blockIdx.x == 0) final_body(out, sm);
}

// ---------------- fallback 3-kernel path ----------------
__global__ void __launch_bounds__(256) convdw_sums_kernel(
        const float* __restrict__ labels, const float* __restrict__ img) {
    __shared__ float4 tA[26 * TAS];
    __shared__ float4 tB[26 * TBS];
    __shared__ float sm[8];
    tileA_body(blockIdx.x, labels, img, tA, tB, sm);
}

__global__ void __launch_bounds__(256) convh_dot_kernel(
        const float* __restrict__ labels, const float* __restrict__ img) {
    __shared__ float4 tile_s[26 * TBS];
    __shared__ float sm[8];
    __shared__ float s_mean;
    tileB_body(blockIdx.x, labels, img, tile_s, sm, &s_mean);
}

__global__ void __launch_bounds__(256) final_kernel(float* __restrict__ out) {
    __shared__ float sm[8];
    final_body(out, sm);
}

extern "C" void kernel_launch(void* const* d_in, const int* in_sizes, int n_in,
                              void* d_out, int out_size, void* d_ws, size_t ws_size,
                              hipStream_t stream) {
    const float* labels = (const float*)d_in[0];   // (2,4,80,80,80) f32
    const float* img    = (const float*)d_in[1];   // (2,1,80,80,80) f32
    float* out = (float*)d_out;                    // 1 float
    (void)d_ws; (void)ws_size;                     // module-scope scratch

    void* args[] = {(void*)&labels, (void*)&img, (void*)&out};
    hipError_t err = hipLaunchCooperativeKernel((const void*)fused_kernel,
                                                dim3(GRID), dim3(256), args, 0, stream);
    if (err != hipSuccess) {
        // deterministic fallback (same math, 3 launches)
        hipLaunchKernelGGL(convdw_sums_kernel, dim3(NBLK), dim3(256), 0, stream, labels, img);
        hipLaunchKernelGGL(convh_dot_kernel,   dim3(NBLK), dim3(256), 0, stream, labels, img);
        hipLaunchKernelGGL(final_kernel,       dim3(1),    dim3(256), 0, stream, out);
    }
}

// Round 8
// 303.783 us; speedup vs baseline: 2.3201x; 2.3201x over previous
//
#include <hip/hip_runtime.h>
#include <math.h>

#define RAD 5
#define SIDE 80
#define SLAB 6400      // 80*80
#define VOL 512000     // 80^3
#define NCH 8          // N*K
#define NCLS 4
#define TW 16          // tile extent along the convolved axis
#define NT 5           // tiles per axis (80/16)
#define NBLK (NCH*SIDE*NT)     // 3200 tiles
#define Q 20           // float4 columns per 80-float row
#define TAS 24         // tA row stride in float4 (96 floats: 2-f4 pad both sides)
#define TBS 21         // tB/tile row stride in float4

// exp(-t^2/32) for t=-5..5 (unnormalized Gaussian, symmetric)
__constant__ float GW[11] = {
    0.45783336177161427f, 0.6065306597126334f, 0.7548396019890073f,
    0.8824969025845955f,  0.969233234476344f,  1.0f,
    0.969233234476344f,   0.8824969025845955f, 0.7548396019890073f,
    0.6065306597126334f,  0.45783336177161427f};

// Module-scope scratch (no d_ws dependence).
// Cross-block scalar data flows ONLY through device-scope atomics (XCD-safe);
// accumulators/tickets are reset by the last block each call, so every launch
// starts from the same state (initializers cover the first call).
__device__ float    g_bufT[(size_t)NCH * VOL];  // d+w-conv'd labels, [c][w][h][d]
__device__ float    g_sums[2 * NCH] = {};       // {S_ip, S_p} per channel (atomic)
__device__ float    g_nd[2 * NCH]   = {};       // {num, den} per channel (atomic)
__device__ float    g_mean[NCH];                // written by K1's last block
__device__ unsigned g_t1 = 0, g_t2 = 0;         // tickets

// K1: per (c, h, w-tile): channel sums + conv D + conv W, transposed store.
// Last block computes per-channel means and self-resets the accumulators.
__global__ void __launch_bounds__(256) convdw_sums_kernel(
        const float* __restrict__ labels, const float* __restrict__ img) {
    const int tile = blockIdx.x;
    const int c   = tile / (SIDE * NT);
    const int rem = tile % (SIDE * NT);
    const int h   = rem / NT;
    const int w0  = (rem % NT) * TW;
    const int n   = c >> 2;

    __shared__ float4 tA[26 * TAS];
    __shared__ float4 tB[26 * TBS];
    __shared__ float sm[8];

    // zero the d-pad columns only (f4 idx 0,1,22,23 per row)
    for (int i = threadIdx.x; i < 26 * 4; i += 256) {
        int r = i >> 2, j = i & 3;
        tA[r * TAS + ((j < 2) ? j : (20 + j))] = make_float4(0.f, 0.f, 0.f, 0.f);
    }
    // load labels rows; OOB halo rows store zero
    const float* labc = labels + ((size_t)c * SIDE + h) * SLAB;   // [w][d] slab
    for (int i = threadIdx.x; i < 26 * Q; i += 256) {
        int r = i / Q, q = i - r * Q;
        int w = w0 - RAD + r;
        float4 v = (w >= 0 && w < SIDE)
                     ? ((const float4*)(labc + (size_t)w * SIDE))[q]
                     : make_float4(0.f, 0.f, 0.f, 0.f);
        tA[r * TAS + 2 + q] = v;
    }
    __syncthreads();

    // channel sums over the central 16 rows
    float sip = 0.f, sp = 0.f;
    const float4* imgc4 = (const float4*)(img + ((((size_t)n * SIDE + h) * SIDE + w0) * SIDE));
    for (int i = threadIdx.x; i < TW * Q; i += 256) {
        int rl = i / Q, q = i - rl * Q;
        float4 l = tA[(rl + RAD) * TAS + 2 + q];
        float4 v = imgc4[i];
        sip += l.x * v.x + l.y * v.y + l.z * v.z + l.w * v.w;
        sp  += l.x + l.y + l.z + l.w;
    }
    // conv along D: register window, 5 b128 reads -> 4 outputs
    for (int i = threadIdx.x; i < 26 * Q; i += 256) {
        int r = i / Q, q = i - r * Q;
        const float4* row = &tA[r * TAS + q];
        float a[20];
        #pragma unroll
        for (int j = 0; j < 5; ++j) {
            float4 v = row[j];
            a[4 * j] = v.x; a[4 * j + 1] = v.y; a[4 * j + 2] = v.z; a[4 * j + 3] = v.w;
        }
        float s0 = 0.f, s1 = 0.f, s2 = 0.f, s3 = 0.f;
        #pragma unroll
        for (int t = 0; t < 11; ++t) {
            float g = GW[t];
            s0 += g * a[t + 3]; s1 += g * a[t + 4];
            s2 += g * a[t + 5]; s3 += g * a[t + 6];
        }
        tB[r * TBS + q] = make_float4(s0, s1, s2, s3);
    }
    // block-reduce the sums
    #pragma unroll
    for (int off = 32; off > 0; off >>= 1) {
        sip += __shfl_down(sip, off);
        sp  += __shfl_down(sp, off);
    }
    const int lane = threadIdx.x & 63;
    const int wid  = threadIdx.x >> 6;
    if (lane == 0) { sm[wid * 2] = sip; sm[wid * 2 + 1] = sp; }
    __syncthreads();   // tB complete + sm visible
    if (threadIdx.x == 0) {
        atomicAdd(&g_sums[2 * c],     sm[0] + sm[2] + sm[4] + sm[6]);
        atomicAdd(&g_sums[2 * c + 1], sm[1] + sm[3] + sm[5] + sm[7]);
    }
    // conv along W + transposed float4 store
    float* outc = g_bufT + (size_t)c * VOL + (size_t)h * SIDE;
    for (int i = threadIdx.x; i < TW * Q; i += 256) {
        int rl = i / Q, q = i - rl * Q;
        float sx = 0.f, sy = 0.f, sz = 0.f, sw = 0.f;
        #pragma unroll
        for (int t = 0; t < 11; ++t) {
            float g = GW[t];
            float4 v = tB[(rl + t) * TBS + q];
            sx += g * v.x; sy += g * v.y; sz += g * v.z; sw += g * v.w;
        }
        ((float4*)(outc + (size_t)(w0 + rl) * SLAB))[q] = make_float4(sx, sy, sz, sw);
    }
    // last-block ticket: compute means, self-reset accumulators + ticket
    __syncthreads();
    if (threadIdx.x == 0) {
        __threadfence();
        unsigned t = atomicAdd(&g_t1, 1u);
        if (t == NBLK - 1) {
            #pragma unroll
            for (int cc = 0; cc < NCH; ++cc) {
                float a = atomicAdd(&g_sums[2 * cc], 0.0f);     // coherent read
                float b = atomicAdd(&g_sums[2 * cc + 1], 0.0f);
                g_mean[cc] = a / (b + 5.12f);                   // VOL*EPS_MEAN
            }
            #pragma unroll
            for (int i = 0; i < 2 * NCH; ++i) atomicExch(&g_sums[i], 0.0f);
            atomicExch(&g_t1, 0u);
        }
    }
}

// K2: per (c, w, h-tile): conv H of g_bufT + fused weight + dot with labels.
// Last block computes the loss scalar and self-resets.
__global__ void __launch_bounds__(256) convh_dot_kernel(
        const float* __restrict__ labels, const float* __restrict__ img,
        float* __restrict__ out) {
    const int tile = blockIdx.x;
    const int c   = tile / (SIDE * NT);
    const int rem = tile % (SIDE * NT);
    const int w   = rem / NT;
    const int h0  = (rem % NT) * TW;
    const int n   = c >> 2;
    const float mean = g_mean[c];    // from K1's last block (kernel boundary)

    __shared__ float4 tile_s[26 * TBS];
    __shared__ float sm[8];

    // load tile (rows contiguous in g_bufT layout), zero OOB halo
    const float4* bc4 = (const float4*)(g_bufT + (size_t)c * VOL + (size_t)w * SLAB);
    for (int i = threadIdx.x; i < 26 * Q; i += 256) {
        int r = i / Q, q = i - r * Q;
        int hh = h0 - RAD + r;
        float4 v = (hh >= 0 && hh < SIDE) ? bc4[hh * Q + q]
                                          : make_float4(0.f, 0.f, 0.f, 0.f);
        tile_s[r * TBS + q] = v;
    }
    __syncthreads();

    const float4* labp4 = (const float4*)(labels + (size_t)c * VOL);
    const float4* imgp4 = (const float4*)(img + (size_t)n * VOL);
    float num = 0.f, den = 0.f;
    for (int i = threadIdx.x; i < TW * Q; i += 256) {
        int hl = i / Q, q = i - hl * Q;
        float sx = 0.f, sy = 0.f, sz = 0.f, sw = 0.f;
        #pragma unroll
        for (int t = 0; t < 11; ++t) {
            float g = GW[t];
            float4 v = tile_s[(hl + t) * TBS + q];
            sx += g * v.x; sy += g * v.y; sz += g * v.z; sw += g * v.w;
        }
        size_t gi = ((size_t)(h0 + hl) * SIDE + w) * Q + q;   // float4 index
        float4 l = labp4[gi];
        float4 v = imgp4[gi];
        float d0 = v.x - mean, d1 = v.y - mean, d2 = v.z - mean, d3 = v.w - mean;
        float q0 = d0 * d0, q1 = d1 * d1, q2 = d2 * d2, q3 = d3 * d3;
        float w0_ = __expf(-q0 * q0), w1_ = __expf(-q1 * q1);
        float w2_ = __expf(-q2 * q2), w3_ = __expf(-q3 * q3);
        num += sx * l.x * w0_ + sy * l.y * w1_ + sz * l.z * w2_ + sw * l.w * w3_;
        den += sx * w0_ + sy * w1_ + sz * w2_ + sw * w3_;
    }
    #pragma unroll
    for (int off = 32; off > 0; off >>= 1) {
        num += __shfl_down(num, off);
        den += __shfl_down(den, off);
    }
    const int lane = threadIdx.x & 63;
    const int wid  = threadIdx.x >> 6;
    if (lane == 0) { sm[wid * 2] = num; sm[wid * 2 + 1] = den; }
    __syncthreads();
    if (threadIdx.x == 0) {
        atomicAdd(&g_nd[2 * c],     sm[0] + sm[2] + sm[4] + sm[6]);
        atomicAdd(&g_nd[2 * c + 1], sm[1] + sm[3] + sm[5] + sm[7]);
        __threadfence();
        unsigned t = atomicAdd(&g_t2, 1u);
        if (t == NBLK - 1) {
            float cn[NCH], cd[NCH];
            #pragma unroll
            for (int cc = 0; cc < NCH; ++cc) {
                cn[cc] = atomicAdd(&g_nd[2 * cc], 0.0f);        // coherent read
                cd[cc] = atomicAdd(&g_nd[2 * cc + 1], 0.0f);
            }
            float loss = 0.f;
            #pragma unroll
            for (int k = 0; k < NCLS; ++k) {
                float r0 = cn[k]        / (cd[k]        + 1e-6f);
                float r1 = cn[NCLS + k] / (cd[NCLS + k] + 1e-6f);
                loss += 0.5f * (fabsf(r0) + fabsf(r1));   // mean over N, sum over K
            }
            out[0] = (float)NCLS - loss;
            #pragma unroll
            for (int i = 0; i < 2 * NCH; ++i) atomicExch(&g_nd[i], 0.0f);
            atomicExch(&g_t2, 0u);
        }
    }
}

extern "C" void kernel_launch(void* const* d_in, const int* in_sizes, int n_in,
                              void* d_out, int out_size, void* d_ws, size_t ws_size,
                              hipStream_t stream) {
    const float* labels = (const float*)d_in[0];   // (2,4,80,80,80) f32
    const float* img    = (const float*)d_in[1];   // (2,1,80,80,80) f32
    float* out = (float*)d_out;                    // 1 float
    (void)d_ws; (void)ws_size;                     // module-scope scratch

    hipLaunchKernelGGL(convdw_sums_kernel, dim3(NBLK), dim3(256), 0, stream, labels, img);
    hipLaunchKernelGGL(convh_dot_kernel,   dim3(NBLK), dim3(256), 0, stream, labels, img, out);
}

// Round 9
// 98.207 us; speedup vs baseline: 7.1767x; 3.0933x over previous
//
#include <hip/hip_runtime.h>
#include <math.h>

#define RAD 5
#define SIDE 80
#define SLAB 6400      // 80*80
#define VOL 512000     // 80^3
#define NCH 8          // N*K
#define NCLS 4
#define TW 16          // K1 tile extent along w
#define NT 5           // w-tiles per axis (80/16)
#define NBLK1 (NCH*SIDE*NT)    // 3200 K1 tiles
#define Q 20           // float4 columns per 80-float row
#define TBS 22         // tB row stride in float4
#define NBLK2 1000     // K2 blocks (256 thr each; 125 blocks per channel)
#define CPB 125        // K2 blocks per channel

// exp(-t^2/32) for t=-5..5 (unnormalized Gaussian, symmetric)
__constant__ float GW[11] = {
    0.45783336177161427f, 0.6065306597126334f, 0.7548396019890073f,
    0.8824969025845955f,  0.969233234476344f,  1.0f,
    0.969233234476344f,   0.8824969025845955f, 0.7548396019890073f,
    0.6065306597126334f,  0.45783336177161427f};

// Module-scope scratch. NO cross-block atomics/fences (R8: they cost ~100 µs/kernel).
// All cross-kernel data flows through per-block slots + kernel boundaries.
__device__ float  g_bufT[(size_t)NCH * VOL];  // d+w-conv'd labels, [c][w][h][d]
__device__ float2 g_part1[NBLK1];             // {S_ip, S_p} per K1 tile
__device__ float2 g_part2[NBLK2];             // {num, den} per K2 block

// K1: per (c, h, w-tile): d-conv via register window from global (no input tile),
// fused channel sums, w-conv via LDS gather, transposed store to g_bufT.
__global__ void __launch_bounds__(256) convdw_sums_kernel(
        const float* __restrict__ labels, const float* __restrict__ img) {
    const int tile = blockIdx.x;
    const int c   = tile / (SIDE * NT);
    const int rem = tile % (SIDE * NT);
    const int h   = rem / NT;
    const int w0  = (rem % NT) * TW;
    const int n   = c >> 2;

    __shared__ float4 tB[26 * TBS];   // d-conv result rows w0-5..w0+20
    __shared__ float sm[8];

    const float4* labc4 = (const float4*)(labels + ((size_t)c * SIDE + h) * SLAB);
    const float4* imgc4 = (const float4*)(img + ((size_t)n * SIDE + h) * SLAB);

    float sip = 0.f, sp = 0.f;
    for (int i = threadIdx.x; i < 26 * Q; i += 256) {
        const int r = i / Q, q = i - (i / Q) * Q;
        const int w = w0 - RAD + r;
        float a[20];
        #pragma unroll
        for (int j = 0; j < 20; ++j) a[j] = 0.f;
        if (w >= 0 && w < SIDE) {
            const float4* row = labc4 + (size_t)w * Q;
            #pragma unroll
            for (int j = 0; j < 5; ++j) {
                int qq = q - 2 + j;
                if (qq >= 0 && qq < Q) {
                    float4 v = row[qq];
                    a[4 * j] = v.x; a[4 * j + 1] = v.y;
                    a[4 * j + 2] = v.z; a[4 * j + 3] = v.w;
                }
            }
            if (r >= RAD && r < RAD + TW) {   // central rows: fused channel sums
                float4 v = imgc4[(size_t)w * Q + q];
                sip += a[8] * v.x + a[9] * v.y + a[10] * v.z + a[11] * v.w;
                sp  += a[8] + a[9] + a[10] + a[11];
            }
        }
        float s0 = 0.f, s1 = 0.f, s2 = 0.f, s3 = 0.f;
        #pragma unroll
        for (int t = 0; t < 11; ++t) {
            float g = GW[t];
            s0 += g * a[t + 3]; s1 += g * a[t + 4];
            s2 += g * a[t + 5]; s3 += g * a[t + 6];
        }
        tB[r * TBS + q] = make_float4(s0, s1, s2, s3);
    }
    // block-reduce sums into sm (visibility covered by the same barrier as tB)
    #pragma unroll
    for (int off = 32; off > 0; off >>= 1) {
        sip += __shfl_down(sip, off);
        sp  += __shfl_down(sp, off);
    }
    const int lane = threadIdx.x & 63;
    const int wid  = threadIdx.x >> 6;
    if (lane == 0) { sm[wid * 2] = sip; sm[wid * 2 + 1] = sp; }
    __syncthreads();
    if (threadIdx.x == 0)
        g_part1[tile] = make_float2(sm[0] + sm[2] + sm[4] + sm[6],
                                    sm[1] + sm[3] + sm[5] + sm[7]);
    // w-conv (11-tap LDS gather) + transposed float4 store
    float* outc = g_bufT + (size_t)c * VOL + (size_t)h * SIDE;
    for (int i = threadIdx.x; i < TW * Q; i += 256) {
        const int rl = i / Q, q = i - (i / Q) * Q;
        float sx = 0.f, sy = 0.f, sz = 0.f, sw = 0.f;
        #pragma unroll
        for (int t = 0; t < 11; ++t) {
            float g = GW[t];
            float4 v = tB[(rl + t) * TBS + q];
            sx += g * v.x; sy += g * v.y; sz += g * v.z; sw += g * v.w;
        }
        ((float4*)(outc + (size_t)(w0 + rl) * SLAB))[q] = make_float4(sx, sy, sz, sw);
    }
}

// K2: register sliding-window conv along H straight from g_bufT (no LDS conv),
// fused weight + dot. Thread = (c, hq, w, q), 4 h-outputs per thread.
__global__ void __launch_bounds__(256) convh_dot_kernel(
        const float* __restrict__ labels, const float* __restrict__ img) {
    const int c = blockIdx.x / CPB;       // block spans exactly one channel
    const int tid = blockIdx.x * 256 + threadIdx.x;
    const int rem = tid % (CPB * 256);    // 0..31999 within channel
    const int hq  = rem / 1600;           // 20 h-quads
    const int r2  = rem % 1600;
    const int w   = r2 / Q;
    const int q   = r2 % Q;
    const int h0  = hq * 4;
    const int n   = c >> 2;

    __shared__ float sm[8];
    __shared__ float s_mean;

    // per-channel mean from K1 partials (block-redundant; L2-resident, 3.2 KB)
    float a = 0.f, b = 0.f;
    for (int t = threadIdx.x; t < SIDE * NT; t += 256) {
        float2 p = g_part1[c * (SIDE * NT) + t];
        a += p.x; b += p.y;
    }
    #pragma unroll
    for (int off = 32; off > 0; off >>= 1) {
        a += __shfl_down(a, off);
        b += __shfl_down(b, off);
    }
    const int lane = threadIdx.x & 63;
    const int wid  = threadIdx.x >> 6;
    if (lane == 0) { sm[wid * 2] = a; sm[wid * 2 + 1] = b; }
    __syncthreads();
    if (threadIdx.x == 0)
        s_mean = (sm[0] + sm[2] + sm[4] + sm[6]) /
                 (sm[1] + sm[3] + sm[5] + sm[7] + 5.12f);   // VOL*EPS_MEAN
    __syncthreads();
    const float mean = s_mean;

    // sliding window: g_bufT[c][w][h0-5 .. h0+8][q]  (14 f4, OOB -> 0)
    const float4* bc4 = (const float4*)g_bufT + (size_t)c * (VOL / 4) + (size_t)w * (SLAB / 4);
    float4 win[14];
    #pragma unroll
    for (int m = 0; m < 14; ++m) {
        int hh = h0 - RAD + m;
        win[m] = (hh >= 0 && hh < SIDE) ? bc4[hh * Q + q]
                                        : make_float4(0.f, 0.f, 0.f, 0.f);
    }
    const float4* labp4 = (const float4*)labels + (size_t)c * (VOL / 4);
    const float4* imgp4 = (const float4*)img + (size_t)n * (VOL / 4);
    float num = 0.f, den = 0.f;
    #pragma unroll
    for (int k = 0; k < 4; ++k) {
        float sx = 0.f, sy = 0.f, sz = 0.f, sw = 0.f;
        #pragma unroll
        for (int t = 0; t < 11; ++t) {
            float g = GW[t];
            float4 v = win[k + t];
            sx += g * v.x; sy += g * v.y; sz += g * v.z; sw += g * v.w;
        }
        size_t gi = (size_t)(h0 + k) * (SLAB / 4) + (size_t)w * Q + q;
        float4 l = labp4[gi];
        float4 v = imgp4[gi];
        float d0 = v.x - mean, d1 = v.y - mean, d2 = v.z - mean, d3 = v.w - mean;
        float q0 = d0 * d0, q1 = d1 * d1, q2 = d2 * d2, q3 = d3 * d3;
        float w0_ = __expf(-q0 * q0), w1_ = __expf(-q1 * q1);
        float w2_ = __expf(-q2 * q2), w3_ = __expf(-q3 * q3);
        num += sx * l.x * w0_ + sy * l.y * w1_ + sz * l.z * w2_ + sw * l.w * w3_;
        den += sx * w0_ + sy * w1_ + sz * w2_ + sw * w3_;
    }
    #pragma unroll
    for (int off = 32; off > 0; off >>= 1) {
        num += __shfl_down(num, off);
        den += __shfl_down(den, off);
    }
    if (lane == 0) { sm[wid * 2] = num; sm[wid * 2 + 1] = den; }
    __syncthreads();
    if (threadIdx.x == 0)
        g_part2[blockIdx.x] = make_float2(sm[0] + sm[2] + sm[4] + sm[6],
                                          sm[1] + sm[3] + sm[5] + sm[7]);
}

// K3: reduce K2's per-block partials -> per-channel ratio -> loss scalar
__global__ void __launch_bounds__(256) final_kernel(float* __restrict__ out) {
    __shared__ float sm[8];
    __shared__ float cn[NCH], cd[NCH];
    const int lane = threadIdx.x & 63;
    const int wid  = threadIdx.x >> 6;
    for (int c = 0; c < NCH; ++c) {
        float a = 0.f, b = 0.f;
        for (int t = threadIdx.x; t < CPB; t += 256) {
            float2 p = g_part2[c * CPB + t];
            a += p.x; b += p.y;
        }
        #pragma unroll
        for (int off = 32; off > 0; off >>= 1) {
            a += __shfl_down(a, off);
            b += __shfl_down(b, off);
        }
        if (lane == 0) { sm[wid * 2] = a; sm[wid * 2 + 1] = b; }
        __syncthreads();
        if (threadIdx.x == 0) {
            cn[c] = sm[0] + sm[2] + sm[4] + sm[6];
            cd[c] = sm[1] + sm[3] + sm[5] + sm[7];
        }
        __syncthreads();
    }
    if (threadIdx.x == 0) {
        float loss = 0.f;
        for (int k = 0; k < NCLS; ++k) {
            float r0 = cn[k]        / (cd[k]        + 1e-6f);
            float r1 = cn[NCLS + k] / (cd[NCLS + k] + 1e-6f);
            loss += 0.5f * (fabsf(r0) + fabsf(r1));   // mean over N=2, sum over K
        }
        out[0] = (float)NCLS - loss;
    }
}

extern "C" void kernel_launch(void* const* d_in, const int* in_sizes, int n_in,
                              void* d_out, int out_size, void* d_ws, size_t ws_size,
                              hipStream_t stream) {
    const float* labels = (const float*)d_in[0];   // (2,4,80,80,80) f32
    const float* img    = (const float*)d_in[1];   // (2,1,80,80,80) f32
    float* out = (float*)d_out;                    // 1 float
    (void)d_ws; (void)ws_size;                     // module-scope scratch

    hipLaunchKernelGGL(convdw_sums_kernel, dim3(NBLK1), dim3(256), 0, stream, labels, img);
    hipLaunchKernelGGL(convh_dot_kernel,   dim3(NBLK2), dim3(256), 0, stream, labels, img);
    hipLaunchKernelGGL(final_kernel,       dim3(1),     dim3(256), 0, stream, out);
}